// Round 2
// baseline (454.630 us; speedup 1.0000x reference)
//
#include <hip/hip_runtime.h>
#include <hip/hip_bf16.h>
#include <math.h>

// MEGConformerLayer: conv block + DeBERTa-v2 attention + FFN, all bf16 MFMA.
// B=8 S=1024 D=512 H=8 DH=64 K=3 FF=1024 BUCKETS=32 SPAN=32
// Workspace budget: 52.7 MB (d_out doubles as the fp32 residual buffer).

#define B_  8
#define S_  1024
#define D_  512
#define H_  8
#define DH_ 64
#define FF_ 1024
#define BS_ (B_*S_)   // 8192

typedef __attribute__((ext_vector_type(8))) short  short8;
typedef __attribute__((ext_vector_type(4))) short  short4v;
typedef __attribute__((ext_vector_type(4))) float  f32x4;
typedef __attribute__((ext_vector_type(4))) int    int4v;

static __device__ __forceinline__ float b2f(short u){
  union { int i; float f; } cv; cv.i = ((int)(unsigned short)u) << 16; return cv.f;
}
static __device__ __forceinline__ short f2b(float f){
  union { float f; unsigned u; } cv; cv.f = f;
  unsigned r = cv.u + 0x7FFFu + ((cv.u >> 16) & 1u);  // RNE
  return (short)(r >> 16);
}
static __device__ __forceinline__ float silu_f(float x){
  return x / (1.f + __expf(-x));
}
static __device__ __forceinline__ f32x4 mfma16(short8 a, short8 b, f32x4 c){
  return __builtin_amdgcn_mfma_f32_16x16x32_bf16(a, b, c, 0, 0, 0);
}

// ---------------- fp32 -> bf16 bulk convert (weights) ----------------
__global__ __launch_bounds__(256) void f2b_kernel(const float* __restrict__ src,
                                                  short* __restrict__ dst, int n){
  int i = (blockIdx.x*256 + threadIdx.x)*4;
  if (i >= n) return;
  float4 v = *(const float4*)(src + i);
  short4v o; o.x = f2b(v.x); o.y = f2b(v.y); o.z = f2b(v.z); o.w = f2b(v.w);
  *(short4v*)(dst + i) = o;
}

// ---------------- LayerNorm (rows of 512), fp32 in -> bf16 out ----------------
__global__ __launch_bounds__(128) void ln_kernel(const float* __restrict__ x,
                                                 const float* __restrict__ g,
                                                 const float* __restrict__ bb,
                                                 short* __restrict__ out){
  int row = blockIdx.x;
  int tid = threadIdx.x;               // 128 threads * float4 = 512
  float4 v = ((const float4*)(x + (size_t)row*D_))[tid];
  float s  = v.x + v.y + v.z + v.w;
  float ss = v.x*v.x + v.y*v.y + v.z*v.z + v.w*v.w;
  #pragma unroll
  for (int off = 32; off; off >>= 1){ s += __shfl_down(s, off); ss += __shfl_down(ss, off); }
  __shared__ float red[4];
  if ((tid & 63) == 0){ red[tid>>6] = s; red[2 + (tid>>6)] = ss; }
  __syncthreads();
  float S  = red[0] + red[1];
  float SS = red[2] + red[3];
  float m   = S * (1.f/D_);
  float var = SS * (1.f/D_) - m*m;
  float rs  = rsqrtf(var + 1e-5f);
  float4 gv = ((const float4*)g)[tid];
  float4 bv = ((const float4*)bb)[tid];
  short4v o;
  o.x = f2b((v.x - m)*rs*gv.x + bv.x);
  o.y = f2b((v.y - m)*rs*gv.y + bv.y);
  o.z = f2b((v.z - m)*rs*gv.z + bv.z);
  o.w = f2b((v.w - m)*rs*gv.w + bv.w);
  *(short4v*)(out + (size_t)row*D_ + tid*4) = o;
}

// ---------------- depthwise conv (K=3, pad 1, per-seq) + SiLU, bf16->bf16 ----------------
__global__ __launch_bounds__(256) void dwconv_kernel(const short* __restrict__ xn,
                                                     const float* __restrict__ w,   // [D,1,3]
                                                     const float* __restrict__ bias,
                                                     short* __restrict__ out){
  int idx = blockIdx.x*256 + threadIdx.x;   // BS_*64 threads, 8 channels each
  int bs  = idx >> 6;
  int d8  = (idx & 63) << 3;
  int s   = bs & (S_-1);
  const short* base = xn + (size_t)bs*D_ + d8;
  short8 z = {};
  short8 xm = (s > 0)     ? *(const short8*)(base - D_) : z;
  short8 xc =               *(const short8*)(base);
  short8 xp = (s < S_-1)  ? *(const short8*)(base + D_) : z;
  short8 o;
  #pragma unroll
  for (int i = 0; i < 8; i++){
    int d = d8 + i;
    float acc = bias[d] + b2f(xm[i])*w[d*3+0] + b2f(xc[i])*w[d*3+1] + b2f(xp[i])*w[d*3+2];
    o[i] = f2b(silu_f(acc));
  }
  *(short8*)(out + (size_t)bs*D_ + d8) = o;
}

// ---------------- GEMM: C[m,n] = sum_k A[m,k]*W[n,k] + bias[n] (+res)(silu) ----------------
// 64x64 tile, BK=64, 4 waves (2x2 of 32x32), mfma 16x16x32 bf16.
// res/of32 may alias (each element read by its writer thread before the write).
template<bool SILU, bool RES, bool OF32, bool OBF>
__global__ __launch_bounds__(256) void gemm_kernel(const short* __restrict__ A,
                                                   const short* __restrict__ W,
                                                   const float* __restrict__ bias,
                                                   const float* res,
                                                   float* of32,
                                                   short* __restrict__ obf,
                                                   int M, int N, int K){
  __shared__ short a_lds[64][72];
  __shared__ short b_lds[64][72];
  int tid = threadIdx.x;
  int w = tid >> 6, lane = tid & 63, quad = lane >> 4, l16 = lane & 15;
  int wm = (w >> 1) * 32, wn = (w & 1) * 32;
  int m0 = blockIdx.y * 64, n0 = blockIdx.x * 64;
  int r0 = tid >> 3, c0 = (tid & 7) * 8;   // chunk 0: rows 0..31
  int r1 = r0 + 32;                         // chunk 1: rows 32..63
  f32x4 acc[2][2] = {};
  for (int kk = 0; kk < K; kk += 64){
    *(int4v*)&a_lds[r0][c0] = *(const int4v*)(A + (size_t)(m0+r0)*K + kk + c0);
    *(int4v*)&a_lds[r1][c0] = *(const int4v*)(A + (size_t)(m0+r1)*K + kk + c0);
    *(int4v*)&b_lds[r0][c0] = *(const int4v*)(W + (size_t)(n0+r0)*K + kk + c0);
    *(int4v*)&b_lds[r1][c0] = *(const int4v*)(W + (size_t)(n0+r1)*K + kk + c0);
    __syncthreads();
    #pragma unroll
    for (int ks = 0; ks < 2; ks++){
      short8 a0 = *(const short8*)&a_lds[wm      + l16][ks*32 + quad*8];
      short8 a1 = *(const short8*)&a_lds[wm + 16 + l16][ks*32 + quad*8];
      short8 b0 = *(const short8*)&b_lds[wn      + l16][ks*32 + quad*8];
      short8 b1 = *(const short8*)&b_lds[wn + 16 + l16][ks*32 + quad*8];
      acc[0][0] = mfma16(a0, b0, acc[0][0]);
      acc[0][1] = mfma16(a0, b1, acc[0][1]);
      acc[1][0] = mfma16(a1, b0, acc[1][0]);
      acc[1][1] = mfma16(a1, b1, acc[1][1]);
    }
    __syncthreads();
  }
  #pragma unroll
  for (int mt = 0; mt < 2; mt++)
    #pragma unroll
    for (int nt = 0; nt < 2; nt++)
      #pragma unroll
      for (int r = 0; r < 4; r++){
        int row = m0 + wm + mt*16 + quad*4 + r;
        int col = n0 + wn + nt*16 + l16;
        float val = acc[mt][nt][r] + bias[col];
        if (SILU) val = val / (1.f + __expf(-val));
        if (RES)  val += res[(size_t)row*N + col];
        if (OF32) of32[(size_t)row*N + col] = val;
        if (OBF)  obf[(size_t)row*N + col] = f2b(val);
      }
}

// ---------------- c2p/p2c position-bias batched GEMM ----------------
// c2p[bs, h*64+r] = sum_d q[bs,h*64+d]*posk[r,h*64+d]; p2c likewise with (k,posq).
__global__ __launch_bounds__(256) void posbias_kernel(const short* __restrict__ q,
                                                      const short* __restrict__ k,
                                                      const short* __restrict__ posk,
                                                      const short* __restrict__ posq,
                                                      short* __restrict__ c2p,
                                                      short* __restrict__ p2c){
  int bsT = blockIdx.x;          // 128 tiles of 64 rows
  int h   = blockIdx.y;
  int tid = threadIdx.x, w = tid >> 6, lane = tid & 63, quad = lane >> 4, l16 = lane & 15;
  int row_a = bsT*64 + w*16 + l16;
  f32x4 accc[4] = {}, accp[4] = {};
  #pragma unroll
  for (int ks = 0; ks < 2; ks++){
    short8 aq = *(const short8*)(q + (size_t)row_a*D_ + h*DH_ + ks*32 + quad*8);
    short8 ak = *(const short8*)(k + (size_t)row_a*D_ + h*DH_ + ks*32 + quad*8);
    #pragma unroll
    for (int nt = 0; nt < 4; nt++){
      short8 bk = *(const short8*)(posk + (size_t)(nt*16+l16)*D_ + h*DH_ + ks*32 + quad*8);
      short8 bq = *(const short8*)(posq + (size_t)(nt*16+l16)*D_ + h*DH_ + ks*32 + quad*8);
      accc[nt] = mfma16(aq, bk, accc[nt]);
      accp[nt] = mfma16(ak, bq, accp[nt]);
    }
  }
  #pragma unroll
  for (int nt = 0; nt < 4; nt++)
    #pragma unroll
    for (int r = 0; r < 4; r++){
      int row = bsT*64 + w*16 + quad*4 + r;
      int col = h*DH_ + nt*16 + l16;
      c2p[(size_t)row*D_ + col] = f2b(accc[nt][r]);
      p2c[(size_t)row*D_ + col] = f2b(accp[nt][r]);
    }
}

// ---------------- flash attention with DeBERTa rel-position bias ----------------
// block = (i-tile 64, h, b); 4 waves x 16 Q rows; online softmax over 16 j-tiles.
__global__ __launch_bounds__(256) void flash_kernel(const short* __restrict__ q,
                                                    const short* __restrict__ k,
                                                    const short* __restrict__ v,
                                                    const short* __restrict__ c2p,
                                                    const short* __restrict__ p2c,
                                                    short* __restrict__ ctx){
  __shared__ short k_lds[64][72];
  __shared__ short vT_lds[64][72];
  __shared__ short c2p_lds[64][72];
  __shared__ short p2c_lds[64][72];
  __shared__ short p_lds[64][72];
  __shared__ signed char tab[2048];

  int it = blockIdx.x, h = blockIdx.y, b = blockIdx.z;
  int i0 = it * 64;
  int tid = threadIdx.x, w = tid >> 6, lane = tid & 63, quad = lane >> 4, l16 = lane & 15;
  const float scale = 0.07216878364f;   // 1/sqrt(DH*3)

  // DeBERTa log-bucket -> clipped index table over delta = i-j in [-1023,1023]
  const float inv_log = 15.f / logf(7.9375f);   // (mid-1)/log((MAX_REL-1)/mid)
  for (int t = tid; t < 2047; t += 256){
    int d = t - 1023;
    int ad = d < 0 ? -d : d;
    int bkt;
    if (ad <= 16) bkt = d;
    else {
      float lp = ceilf(logf((float)ad * (1.f/16.f)) * inv_log) + 16.f;
      int ilp = (int)lp;
      bkt = (d > 0) ? ilp : -ilp;
    }
    int idx = bkt + 32;
    idx = idx < 0 ? 0 : (idx > 63 ? 63 : idx);
    tab[t] = (signed char)idx;
  }
  // stage c2p rows for this i-tile
  for (int c = tid; c < 512; c += 256){
    int r = c >> 3, cc = (c & 7) * 8;
    *(int4v*)&c2p_lds[r][cc] = *(const int4v*)(c2p + (size_t)(b*S_ + i0 + r)*D_ + h*DH_ + cc);
  }
  // Q fragments (A-layout: m=l16, k=quad*8+j)
  short8 qf[2];
  {
    size_t row = (size_t)(b*S_ + i0 + w*16 + l16);
    qf[0] = *(const short8*)(q + row*D_ + h*DH_ +      quad*8);
    qf[1] = *(const short8*)(q + row*D_ + h*DH_ + 32 + quad*8);
  }
  f32x4 o_acc[4] = {};
  float mrow[4] = {-INFINITY, -INFINITY, -INFINITY, -INFINITY};
  float lrow[4] = {};
  __syncthreads();

  for (int jt = 0; jt < 16; jt++){
    int j0 = jt * 64;
    for (int c = tid; c < 512; c += 256){
      int r = c >> 3, cc = (c & 7) * 8;
      size_t grow = (size_t)(b*S_ + j0 + r);
      *(int4v*)&k_lds[r][cc]   = *(const int4v*)(k   + grow*D_ + h*DH_ + cc);
      *(int4v*)&p2c_lds[r][cc] = *(const int4v*)(p2c + grow*D_ + h*DH_ + cc);
      short8 vv = *(const short8*)(v + grow*D_ + h*DH_ + cc);
      #pragma unroll
      for (int ii = 0; ii < 8; ii++) vT_lds[cc+ii][r] = vv[ii];   // transpose for B-operand
    }
    __syncthreads();

    // S = Q K^T  (per wave: 16 rows x 64 cols)
    f32x4 sfr[4];
    #pragma unroll
    for (int nt = 0; nt < 4; nt++){
      f32x4 a = {};
      a = mfma16(qf[0], *(const short8*)&k_lds[nt*16+l16][     quad*8], a);
      a = mfma16(qf[1], *(const short8*)&k_lds[nt*16+l16][32 + quad*8], a);
      sfr[nt] = a;
    }
    // add (c2p + p2c) gathers, apply scale
    float sval[4][4];
    #pragma unroll
    for (int nt = 0; nt < 4; nt++){
      int jloc = nt*16 + l16;
      int jg = j0 + jloc;
      #pragma unroll
      for (int r = 0; r < 4; r++){
        int iloc = w*16 + quad*4 + r;
        int idx  = tab[(i0 + iloc) - jg + 1023];
        sval[nt][r] = (sfr[nt][r] + b2f(c2p_lds[iloc][idx]) + b2f(p2c_lds[jloc][idx])) * scale;
      }
    }
    // online softmax (rows live in one quad: shfl-xor over 16 lanes)
    float mnew[4], alpha[4], lsum[4];
    #pragma unroll
    for (int r = 0; r < 4; r++){
      float mx = fmaxf(fmaxf(sval[0][r], sval[1][r]), fmaxf(sval[2][r], sval[3][r]));
      #pragma unroll
      for (int off = 8; off; off >>= 1) mx = fmaxf(mx, __shfl_xor(mx, off));
      mnew[r]  = fmaxf(mrow[r], mx);
      alpha[r] = __expf(mrow[r] - mnew[r]);
      lsum[r]  = 0.f;
    }
    #pragma unroll
    for (int nt = 0; nt < 4; nt++)
      #pragma unroll
      for (int r = 0; r < 4; r++){
        float p = __expf(sval[nt][r] - mnew[r]);
        sval[nt][r] = p;
        lsum[r] += p;
      }
    #pragma unroll
    for (int r = 0; r < 4; r++){
      #pragma unroll
      for (int off = 8; off; off >>= 1) lsum[r] += __shfl_xor(lsum[r], off);
      lrow[r] = lrow[r]*alpha[r] + lsum[r];
      mrow[r] = mnew[r];
    }
    // P -> LDS (C-layout to A-layout round trip), rescale O, then O += P V
    #pragma unroll
    for (int nt = 0; nt < 4; nt++)
      #pragma unroll
      for (int r = 0; r < 4; r++)
        p_lds[w*16 + quad*4 + r][nt*16 + l16] = f2b(sval[nt][r]);
    #pragma unroll
    for (int nt = 0; nt < 4; nt++)
      #pragma unroll
      for (int r = 0; r < 4; r++) o_acc[nt][r] *= alpha[r];
    __syncthreads();   // cross-lane LDS visibility before A-frag reads
    short8 pf0 = *(const short8*)&p_lds[w*16 + l16][     quad*8];
    short8 pf1 = *(const short8*)&p_lds[w*16 + l16][32 + quad*8];
    #pragma unroll
    for (int nt = 0; nt < 4; nt++){
      o_acc[nt] = mfma16(pf0, *(const short8*)&vT_lds[nt*16+l16][     quad*8], o_acc[nt]);
      o_acc[nt] = mfma16(pf1, *(const short8*)&vT_lds[nt*16+l16][32 + quad*8], o_acc[nt]);
    }
    __syncthreads();   // protect k/vT/p2c/p before next stage
  }
  #pragma unroll
  for (int nt = 0; nt < 4; nt++)
    #pragma unroll
    for (int r = 0; r < 4; r++){
      size_t row = (size_t)(b*S_ + i0 + w*16 + quad*4 + r);
      ctx[row*D_ + h*DH_ + nt*16 + l16] = f2b(o_acc[nt][r] / lrow[r]);
    }
}

// ---------------- workspace layout (bytes) — total 55,246,848 (~52.7 MB) ----------------
// Aliases: DWS = C2P span (DWS dead before posbias writes C2P);
//          CTX = XN span (XN dead after q/k/v gemms, rewritten by ln3 later);
//          FFH = Q..K span (dead after flash);
//          fp32 residual chain lives in d_out (written by pw-gemm, read+rewritten
//          in-place by o-gemm and ffn2-gemm — per-element same-thread RMW).
static const size_t OFF_XN   = 0;           // bf16 8192x512
static const size_t OFF_Q    = 8388608;     // bf16 8192x512
static const size_t OFF_K    = 16777216;    // bf16 8192x512
static const size_t OFF_V    = 25165824;    // bf16 8192x512
static const size_t OFF_C2P  = 33554432;    // bf16 8192x512 (aliased: DWS)
static const size_t OFF_P2C  = 41943040;    // bf16 8192x512
static const size_t OFF_WPW  = 50331648;    // bf16 512x512
static const size_t OFF_WQ   = 50855936;
static const size_t OFF_WK   = 51380224;
static const size_t OFF_WV   = 51904512;
static const size_t OFF_WO   = 52428800;
static const size_t OFF_W1   = 52953088;    // bf16 1024x512
static const size_t OFF_W2   = 54001664;    // bf16 512x1024
static const size_t OFF_REL  = 55050240;    // bf16 64x512
static const size_t OFF_POSK = 55115776;    // bf16 64x512
static const size_t OFF_POSQ = 55181312;    // bf16 64x512

extern "C" void kernel_launch(void* const* d_in, const int* in_sizes, int n_in,
                              void* d_out, int out_size, void* d_ws, size_t ws_size,
                              hipStream_t stream){
  const float* x    = (const float*)d_in[0];
  const float* ln1g = (const float*)d_in[1];
  const float* ln1b = (const float*)d_in[2];
  const float* dww  = (const float*)d_in[3];
  const float* dwb  = (const float*)d_in[4];
  const float* pww  = (const float*)d_in[5];
  const float* pwb  = (const float*)d_in[6];
  const float* ln2g = (const float*)d_in[7];
  const float* ln2b = (const float*)d_in[8];
  const float* qw   = (const float*)d_in[9];
  const float* qb   = (const float*)d_in[10];
  const float* kw   = (const float*)d_in[11];
  const float* kb   = (const float*)d_in[12];
  const float* vw   = (const float*)d_in[13];
  const float* vb   = (const float*)d_in[14];
  const float* ow   = (const float*)d_in[15];
  const float* ob   = (const float*)d_in[16];
  const float* rel  = (const float*)d_in[17];
  const float* ln3g = (const float*)d_in[18];
  const float* ln3b = (const float*)d_in[19];
  const float* w1   = (const float*)d_in[20];
  const float* b1   = (const float*)d_in[21];
  const float* w2   = (const float*)d_in[22];
  const float* b2   = (const float*)d_in[23];
  float* out = (float*)d_out;
  char* ws = (char*)d_ws;

  short* XN   = (short*)(ws + OFF_XN);
  short* Q    = (short*)(ws + OFF_Q);
  short* Kb_  = (short*)(ws + OFF_K);
  short* V    = (short*)(ws + OFF_V);
  short* C2P  = (short*)(ws + OFF_C2P);
  short* P2C  = (short*)(ws + OFF_P2C);
  short* WPW  = (short*)(ws + OFF_WPW);
  short* WQ   = (short*)(ws + OFF_WQ);
  short* WK   = (short*)(ws + OFF_WK);
  short* WV   = (short*)(ws + OFF_WV);
  short* WO   = (short*)(ws + OFF_WO);
  short* W1B  = (short*)(ws + OFF_W1);
  short* W2B  = (short*)(ws + OFF_W2);
  short* RELB = (short*)(ws + OFF_REL);
  short* POSK = (short*)(ws + OFF_POSK);
  short* POSQ = (short*)(ws + OFF_POSQ);
  short* DWS  = C2P;     // alias: conv-silu output, dead before C2P written
  short* CTX  = XN;      // alias: attention context, XN dead after q/k/v
  short* FFH  = Q;       // alias: FFN hidden (16 MB over Q+K spans)

  // weight conversions
  f2b_kernel<<<256, 256, 0, stream>>>(pww, WPW, 262144);
  f2b_kernel<<<256, 256, 0, stream>>>(qw,  WQ,  262144);
  f2b_kernel<<<256, 256, 0, stream>>>(kw,  WK,  262144);
  f2b_kernel<<<256, 256, 0, stream>>>(vw,  WV,  262144);
  f2b_kernel<<<256, 256, 0, stream>>>(ow,  WO,  262144);
  f2b_kernel<<<512, 256, 0, stream>>>(w1,  W1B, 524288);
  f2b_kernel<<<512, 256, 0, stream>>>(w2,  W2B, 524288);
  f2b_kernel<<<32,  256, 0, stream>>>(rel, RELB, 32768);

  // conv block: out = x + pw(silu(dwconv(ln1(x))))
  ln_kernel<<<BS_, 128, 0, stream>>>(x, ln1g, ln1b, XN);
  dwconv_kernel<<<2048, 256, 0, stream>>>(XN, dww, dwb, DWS);
  gemm_kernel<false,true,true,false><<<dim3(8,128), 256, 0, stream>>>(
      DWS, WPW, pwb, x, out, nullptr, BS_, 512, 512);

  // attention block
  ln_kernel<<<BS_, 128, 0, stream>>>(out, ln2g, ln2b, XN);
  gemm_kernel<false,false,false,true><<<dim3(8,128), 256, 0, stream>>>(
      XN, WQ, qb, nullptr, nullptr, Q,   BS_, 512, 512);
  gemm_kernel<false,false,false,true><<<dim3(8,128), 256, 0, stream>>>(
      XN, WK, kb, nullptr, nullptr, Kb_, BS_, 512, 512);
  gemm_kernel<false,false,false,true><<<dim3(8,128), 256, 0, stream>>>(
      XN, WV, vb, nullptr, nullptr, V,   BS_, 512, 512);
  gemm_kernel<false,false,false,true><<<dim3(8,1), 256, 0, stream>>>(
      RELB, WK, kb, nullptr, nullptr, POSK, 64, 512, 512);
  gemm_kernel<false,false,false,true><<<dim3(8,1), 256, 0, stream>>>(
      RELB, WQ, qb, nullptr, nullptr, POSQ, 64, 512, 512);
  posbias_kernel<<<dim3(128,8), 256, 0, stream>>>(Q, Kb_, POSK, POSQ, C2P, P2C);
  flash_kernel<<<dim3(16,8,8), 256, 0, stream>>>(Q, Kb_, V, C2P, P2C, CTX);
  gemm_kernel<false,true,true,false><<<dim3(8,128), 256, 0, stream>>>(
      CTX, WO, ob, out, out, nullptr, BS_, 512, 512);

  // FFN block: out += w2 @ silu(w1 @ ln3(out))
  ln_kernel<<<BS_, 128, 0, stream>>>(out, ln3g, ln3b, XN);
  gemm_kernel<true,false,false,true><<<dim3(16,128), 256, 0, stream>>>(
      XN, W1B, b1, nullptr, nullptr, FFH, BS_, 1024, 512);
  gemm_kernel<false,true,true,false><<<dim3(8,128), 256, 0, stream>>>(
      FFH, W2B, b2, out, out, nullptr, BS_, 512, 1024);
}